// Round 1
// baseline (461.112 us; speedup 1.0000x reference)
//
#include <hip/hip_runtime.h>
#include <math.h>

// ---------------------------------------------------------------------------
// GCN 2-layer + two heads, fp32, MI355X.
// Pipeline:
//   1. deg histogram (atomics) -> CSR build (shfl scan, 3 tiny kernels)
//   2. hs0 = dinv * (x @ W0)            [LDS-tiled fp32 GEMM, fused row scale]
//   3. h1  = relu(dinv*(sum_nb hs0) + b0)   [CSR gather aggregate, wave/node]
//   4. hs1 = dinv * (h1 @ W1)
//   5. h   = dinv*(sum_nb hs1) + b1  -> d_out[0:ND]
//   6. xv  = relu(h @ Wv + bv)       -> d_out[ND:2ND]
//   7. xt  = relu(h @ Wt + bt)       -> d_out[2ND:3ND]
// ---------------------------------------------------------------------------

#define DFEAT 128

__global__ __launch_bounds__(256) void count_deg_k(const int* __restrict__ dst,
                                                   int* __restrict__ deg, int E) {
    int e = blockIdx.x * 256 + threadIdx.x;
    if (e < E) atomicAdd(&deg[dst[e]], 1);
}

// local exclusive scan per 64-chunk (one wave per chunk)
__global__ __launch_bounds__(256) void scan_local_k(const int* __restrict__ deg,
                                                    int* __restrict__ row_ptr,
                                                    int* __restrict__ chunk_sums,
                                                    int n) {
    int wave = blockIdx.x * 4 + (threadIdx.x >> 6);
    int lane = threadIdx.x & 63;
    int nchunks = (n + 63) >> 6;
    if (wave >= nchunks) return;
    int i = wave * 64 + lane;
    int v = (i < n) ? deg[i] : 0;
    int x = v;
#pragma unroll
    for (int off = 1; off < 64; off <<= 1) {
        int y = __shfl_up(x, off);
        if (lane >= off) x += y;
    }
    if (i < n) row_ptr[i] = x - v;      // local exclusive
    if (lane == 63) chunk_sums[wave] = x;
}

// single-block exclusive scan of chunk sums (nchunks <= 1024)
__global__ __launch_bounds__(1024) void scan_chunks_k(int* __restrict__ a, int nchunks) {
    __shared__ int s[1024];
    int tid = threadIdx.x;
    int v = (tid < nchunks) ? a[tid] : 0;
    s[tid] = v;
    __syncthreads();
    int x = v;
    for (int off = 1; off < 1024; off <<= 1) {
        int y = (tid >= off) ? s[tid - off] : 0;
        __syncthreads();
        x += y;
        s[tid] = x;
        __syncthreads();
    }
    if (tid < nchunks) a[tid] = x - v;  // exclusive
}

__global__ __launch_bounds__(256) void finalize_csr_k(int* __restrict__ row_ptr,
                                                      const int* __restrict__ chunk_offs,
                                                      int* __restrict__ cursor,
                                                      const int* __restrict__ deg,
                                                      float* __restrict__ dinv,
                                                      int n, int E) {
    int i = blockIdx.x * 256 + threadIdx.x;
    if (i < n) {
        int rp = row_ptr[i] + chunk_offs[i >> 6];
        row_ptr[i] = rp;
        cursor[i] = rp;
        dinv[i] = rsqrtf((float)(deg[i] + 1));   // +1 = self loop
    }
    if (i == 0) row_ptr[n] = E;
}

__global__ __launch_bounds__(256) void fill_csr_k(const int* __restrict__ src,
                                                  const int* __restrict__ dst,
                                                  int* __restrict__ cursor,
                                                  int* __restrict__ col_idx, int E) {
    int e = blockIdx.x * 256 + threadIdx.x;
    if (e < E) {
        int pos = atomicAdd(&cursor[dst[e]], 1);
        col_idx[pos] = src[e];
    }
}

// ---------------------------------------------------------------------------
// GEMM: Y[M x 128] = op( (X[M x 128] @ W[128 x 128]) * rowscale + bias )
// 64-row tile per block, 256 threads, thread tile 8 rows x 4 cols.
// LDS: W k-slab 64x128 (32KB) + X tile 64x64 (16KB) = 48KB -> 3 blocks/CU.
// X reads from LDS are 32-lane broadcasts (free); W reads are float4.
// ---------------------------------------------------------------------------
template <bool SCALE, bool BIAS, bool RELU>
__global__ __launch_bounds__(256) void gemm128_k(const float* __restrict__ X,
                                                 const float* __restrict__ W,
                                                 const float* __restrict__ scale,
                                                 const float* __restrict__ bias,
                                                 float* __restrict__ Y, int M) {
    __shared__ float Ws[64 * 128];
    __shared__ float Xs[64 * 64];
    const int tid = threadIdx.x;
    const int c4 = tid & 31;   // col group: cols 4*c4..4*c4+3
    const int rg = tid >> 5;   // row group: rows rg*8..rg*8+7
    const int m0 = blockIdx.x * 64;

    float acc[8][4];
#pragma unroll
    for (int r = 0; r < 8; ++r)
#pragma unroll
        for (int c = 0; c < 4; ++c) acc[r][c] = 0.f;

    for (int k0 = 0; k0 < 128; k0 += 64) {
        // stage W slab: 64x128 floats = 2048 float4, 8 per thread, coalesced
#pragma unroll
        for (int j = 0; j < 8; ++j) {
            int lin = tid + j * 256;            // float4 index
            int kk = lin >> 5, cc = lin & 31;
            float4 w4 = ((const float4*)(W + (size_t)(k0 + kk) * 128))[cc];
            ((float4*)Ws)[kk * 32 + cc] = w4;
        }
        // stage X tile: 64 rows x 64 k = 1024 float4, 4 per thread, coalesced
#pragma unroll
        for (int j = 0; j < 4; ++j) {
            int lin = tid + j * 256;
            int r = lin >> 4, kk4 = lin & 15;
            int row = m0 + r;
            float4 v = make_float4(0.f, 0.f, 0.f, 0.f);
            if (row < M) v = ((const float4*)(X + (size_t)row * 128 + k0))[kk4];
            ((float4*)Xs)[r * 16 + kk4] = v;
        }
        __syncthreads();

#pragma unroll 8
        for (int kk = 0; kk < 64; ++kk) {
            float4 w4 = ((const float4*)Ws)[kk * 32 + c4];
#pragma unroll
            for (int rr = 0; rr < 8; ++rr) {
                float xv = Xs[(rg * 8 + rr) * 64 + kk];   // 32-lane broadcast
                acc[rr][0] = fmaf(xv, w4.x, acc[rr][0]);
                acc[rr][1] = fmaf(xv, w4.y, acc[rr][1]);
                acc[rr][2] = fmaf(xv, w4.z, acc[rr][2]);
                acc[rr][3] = fmaf(xv, w4.w, acc[rr][3]);
            }
        }
        __syncthreads();
    }

    float4 b4 = make_float4(0.f, 0.f, 0.f, 0.f);
    if (BIAS) b4 = ((const float4*)bias)[c4];
#pragma unroll
    for (int rr = 0; rr < 8; ++rr) {
        int row = m0 + rg * 8 + rr;
        if (row < M) {
            float4 o;
            o.x = acc[rr][0]; o.y = acc[rr][1]; o.z = acc[rr][2]; o.w = acc[rr][3];
            if (SCALE) {
                float s = scale[row];
                o.x *= s; o.y *= s; o.z *= s; o.w *= s;
            }
            if (BIAS) { o.x += b4.x; o.y += b4.y; o.z += b4.z; o.w += b4.w; }
            if (RELU) {
                o.x = fmaxf(o.x, 0.f); o.y = fmaxf(o.y, 0.f);
                o.z = fmaxf(o.z, 0.f); o.w = fmaxf(o.w, 0.f);
            }
            ((float4*)(Y + (size_t)row * 128))[c4] = o;
        }
    }
}

// ---------------------------------------------------------------------------
// Aggregate: out[i] = op( dinv[i] * (hs[i] + sum_{e in CSR[i]} hs[col[e]]) + b )
// One wave per node, float2 per lane (128 cols / 64 lanes). Neighbor rows are
// 512B coalesced reads; indices broadcast via __shfl.
// ---------------------------------------------------------------------------
template <bool RELU>
__global__ __launch_bounds__(256) void agg_k(const float* __restrict__ hs,
                                             const int* __restrict__ row_ptr,
                                             const int* __restrict__ col_idx,
                                             const float* __restrict__ dinv,
                                             const float* __restrict__ bias,
                                             float* __restrict__ out, int n) {
    int wave = blockIdx.x * 4 + (threadIdx.x >> 6);
    int lane = threadIdx.x & 63;
    int nwaves = gridDim.x * 4;
    float2 b2 = ((const float2*)bias)[lane];

    for (int i = wave; i < n; i += nwaves) {
        float2 acc = ((const float2*)(hs + (size_t)i * DFEAT))[lane];  // self loop
        int s = row_ptr[i], e = row_ptr[i + 1];
        for (int base = s; base < e; base += 64) {
            int cnt = min(64, e - base);
            int idx = (base + lane < e) ? col_idx[base + lane] : 0;
            int j = 0;
            for (; j + 4 <= cnt; j += 4) {
                int s0 = __shfl(idx, j);
                int s1 = __shfl(idx, j + 1);
                int s2 = __shfl(idx, j + 2);
                int s3 = __shfl(idx, j + 3);
                float2 v0 = ((const float2*)(hs + (size_t)s0 * DFEAT))[lane];
                float2 v1 = ((const float2*)(hs + (size_t)s1 * DFEAT))[lane];
                float2 v2 = ((const float2*)(hs + (size_t)s2 * DFEAT))[lane];
                float2 v3 = ((const float2*)(hs + (size_t)s3 * DFEAT))[lane];
                acc.x += (v0.x + v1.x) + (v2.x + v3.x);
                acc.y += (v0.y + v1.y) + (v2.y + v3.y);
            }
            for (; j < cnt; ++j) {
                int sj = __shfl(idx, j);
                float2 v = ((const float2*)(hs + (size_t)sj * DFEAT))[lane];
                acc.x += v.x;
                acc.y += v.y;
            }
        }
        float di = dinv[i];
        float ox = fmaf(acc.x, di, b2.x);
        float oy = fmaf(acc.y, di, b2.y);
        if (RELU) { ox = fmaxf(ox, 0.f); oy = fmaxf(oy, 0.f); }
        ((float2*)(out + (size_t)i * DFEAT))[lane] = make_float2(ox, oy);
    }
}

// ---------------------------------------------------------------------------

static inline size_t align_up(size_t x, size_t a) { return (x + a - 1) & ~(a - 1); }

extern "C" void kernel_launch(void* const* d_in, const int* in_sizes, int n_in,
                              void* d_out, int out_size, void* d_ws, size_t ws_size,
                              hipStream_t stream) {
    const float* x  = (const float*)d_in[0];
    const int*   ei = (const int*)d_in[1];
    const float* W0 = (const float*)d_in[2];
    const float* b0 = (const float*)d_in[3];
    const float* W1 = (const float*)d_in[4];
    const float* b1 = (const float*)d_in[5];
    const float* Wv = (const float*)d_in[6];
    const float* bv = (const float*)d_in[7];
    const float* Wt = (const float*)d_in[8];
    const float* bt = (const float*)d_in[9];

    const int N = in_sizes[0] / DFEAT;
    const int E = in_sizes[1] / 2;
    const int* src = ei;
    const int* dst = ei + E;

    const int nchunks = (N + 63) >> 6;

    // workspace carve-up
    char* w = (char*)d_ws;
    int* deg        = (int*)w;  w += align_up((size_t)N * 4, 256);
    int* row_ptr    = (int*)w;  w += align_up((size_t)(N + 1) * 4, 256);
    int* cursor     = (int*)w;  w += align_up((size_t)N * 4, 256);
    int* chunk_sums = (int*)w;  w += align_up((size_t)(nchunks + 1) * 4, 256);
    int* col_idx    = (int*)w;  w += align_up((size_t)E * 4, 256);
    float* dinv     = (float*)w; w += align_up((size_t)N * 4, 256);
    float* hs       = (float*)w; w += align_up((size_t)N * DFEAT * 4, 256);
    float* h1       = (float*)w; w += align_up((size_t)N * DFEAT * 4, 256);

    float* out_h = (float*)d_out;
    float* out_v = out_h + (size_t)N * DFEAT;
    float* out_t = out_h + 2 * (size_t)N * DFEAT;

    const int eb = (E + 255) / 256;
    const int nb = (N + 255) / 256;
    const int gemm_blocks = (N + 63) / 64;
    const int agg_blocks = 784;   // 4 waves each -> ~12 waves/CU

    // 1. CSR build
    hipMemsetAsync(deg, 0, (size_t)N * 4, stream);
    count_deg_k<<<eb, 256, 0, stream>>>(dst, deg, E);
    scan_local_k<<<(nchunks + 3) / 4, 256, 0, stream>>>(deg, row_ptr, chunk_sums, N);
    scan_chunks_k<<<1, 1024, 0, stream>>>(chunk_sums, nchunks);
    finalize_csr_k<<<nb, 256, 0, stream>>>(row_ptr, chunk_sums, cursor, deg, dinv, N, E);
    fill_csr_k<<<eb, 256, 0, stream>>>(src, dst, cursor, col_idx, E);

    // 2. layer 0: hs = dinv * (x @ W0)
    gemm128_k<true, false, false><<<gemm_blocks, 256, 0, stream>>>(x, W0, dinv, nullptr, hs, N);
    // 3. h1 = relu(dinv * agg(hs) + b0)
    agg_k<true><<<agg_blocks, 256, 0, stream>>>(hs, row_ptr, col_idx, dinv, b0, h1, N);
    // 4. layer 1: hs = dinv * (h1 @ W1)
    gemm128_k<true, false, false><<<gemm_blocks, 256, 0, stream>>>(h1, W1, dinv, nullptr, hs, N);
    // 5. h = dinv * agg(hs) + b1 -> out
    agg_k<false><<<agg_blocks, 256, 0, stream>>>(hs, row_ptr, col_idx, dinv, b1, out_h, N);
    // 6/7. heads
    gemm128_k<false, true, true><<<gemm_blocks, 256, 0, stream>>>(out_h, Wv, nullptr, bv, out_v, N);
    gemm128_k<false, true, true><<<gemm_blocks, 256, 0, stream>>>(out_h, Wt, nullptr, bt, out_t, N);
}

// Round 2
// 362.835 us; speedup vs baseline: 1.2709x; 1.2709x over previous
//
#include <hip/hip_runtime.h>
#include <math.h>

// ---------------------------------------------------------------------------
// GCN 2-layer + two heads, fp32, MI355X.
//   CSR build (histogram + shfl scan) ->
//   GEMMs via split-bf16 MFMA (hi/lo, 3 mfma ~= fp32 precision) ->
//   CSR gather aggregate (wave/node, unroll-8, full occupancy).
// ---------------------------------------------------------------------------

#define DFEAT 128

using short8  = __attribute__((ext_vector_type(8))) short;
using floatx4 = __attribute__((ext_vector_type(4))) float;

__device__ __forceinline__ unsigned short f2bf_rne(float x) {
    unsigned u = __float_as_uint(x);
    unsigned r = u + 0x7FFFu + ((u >> 16) & 1u);
    return (unsigned short)(r >> 16);
}

// ---------------------------- CSR build ------------------------------------

__global__ __launch_bounds__(256) void count_deg_k(const int* __restrict__ dst,
                                                   int* __restrict__ deg, int E) {
    int e = blockIdx.x * 256 + threadIdx.x;
    if (e < E) atomicAdd(&deg[dst[e]], 1);
}

__global__ __launch_bounds__(256) void scan_local_k(const int* __restrict__ deg,
                                                    int* __restrict__ row_ptr,
                                                    int* __restrict__ chunk_sums,
                                                    int n) {
    int wave = blockIdx.x * 4 + (threadIdx.x >> 6);
    int lane = threadIdx.x & 63;
    int nchunks = (n + 63) >> 6;
    if (wave >= nchunks) return;
    int i = wave * 64 + lane;
    int v = (i < n) ? deg[i] : 0;
    int x = v;
#pragma unroll
    for (int off = 1; off < 64; off <<= 1) {
        int y = __shfl_up(x, off);
        if (lane >= off) x += y;
    }
    if (i < n) row_ptr[i] = x - v;
    if (lane == 63) chunk_sums[wave] = x;
}

__global__ __launch_bounds__(1024) void scan_chunks_k(int* __restrict__ a, int nchunks) {
    __shared__ int s[1024];
    int tid = threadIdx.x;
    int v = (tid < nchunks) ? a[tid] : 0;
    s[tid] = v;
    __syncthreads();
    int x = v;
    for (int off = 1; off < 1024; off <<= 1) {
        int y = (tid >= off) ? s[tid - off] : 0;
        __syncthreads();
        x += y;
        s[tid] = x;
        __syncthreads();
    }
    if (tid < nchunks) a[tid] = x - v;
}

__global__ __launch_bounds__(256) void finalize_csr_k(int* __restrict__ row_ptr,
                                                      const int* __restrict__ chunk_offs,
                                                      int* __restrict__ cursor,
                                                      const int* __restrict__ deg,
                                                      float* __restrict__ dinv,
                                                      int n, int E) {
    int i = blockIdx.x * 256 + threadIdx.x;
    if (i < n) {
        int rp = row_ptr[i] + chunk_offs[i >> 6];
        row_ptr[i] = rp;
        cursor[i] = rp;
        dinv[i] = rsqrtf((float)(deg[i] + 1));   // +1 self loop
    }
    if (i == 0) row_ptr[n] = E;
}

__global__ __launch_bounds__(256) void fill_csr_k(const int* __restrict__ src,
                                                  const int* __restrict__ dst,
                                                  int* __restrict__ cursor,
                                                  int* __restrict__ col_idx, int E) {
    int e = blockIdx.x * 256 + threadIdx.x;
    if (e < E) {
        int pos = atomicAdd(&cursor[dst[e]], 1);
        col_idx[pos] = src[e];
    }
}

// ------------------------- W pre-split to MFMA frags ------------------------
// Fragment layout (16x16x32 bf16): for col-tile t (0..7), K-step s (0..3):
//   64 lanes x 8 bf16 contiguous; lane reads B[k][n], n = t*16 + (lane&15),
//   k = s*32 + (lane>>4)*8 + j.  Flat index i = ((t*4+s)*64 + lane)*8 + j.
__global__ __launch_bounds__(256) void prep_w_k(const float* __restrict__ W,
                                                short* __restrict__ hi,
                                                short* __restrict__ lo) {
    int i = blockIdx.x * 256 + threadIdx.x;     // 0..16383
    int j = i & 7;
    int lane = (i >> 3) & 63;
    int ts = i >> 9;                            // 0..31
    int s = ts & 3, t = ts >> 2;
    int k = s * 32 + (lane >> 4) * 8 + j;
    int n = t * 16 + (lane & 15);
    float x = W[k * 128 + n];
    unsigned short h = f2bf_rne(x);
    float res = x - __uint_as_float(((unsigned)h) << 16);
    hi[i] = (short)h;
    lo[i] = (short)f2bf_rne(res);
}

// ----------------------- GEMM via split-bf16 MFMA ---------------------------
// Y[M x 128] = op( (X @ W) * rowscale + bias ).  Block = 256 thr = 4 waves,
// 32 rows/wave -> 128 rows/block.  W frags (hi+lo, 64KB) staged to LDS once.
// Per wave: A streamed from global, split in regs; 4 Ksteps x 8 tiles x 6 mfma.
template <bool SCALE, bool BIAS, bool RELU>
__global__ __launch_bounds__(256) void gemm_mfma_k(const float* __restrict__ X,
                                                   const short* __restrict__ Whi,
                                                   const short* __restrict__ Wlo,
                                                   const float* __restrict__ scale,
                                                   const float* __restrict__ bias,
                                                   float* __restrict__ Y, int M) {
    __shared__ short WhiS[16384];
    __shared__ short WloS[16384];
    const int tid = threadIdx.x;

    // stage frags: 2 x 32KB = 2 x 2048 float4, 8 per thread each, coalesced
#pragma unroll
    for (int j = 0; j < 8; ++j)
        ((float4*)WhiS)[tid + j * 256] = ((const float4*)Whi)[tid + j * 256];
#pragma unroll
    for (int j = 0; j < 8; ++j)
        ((float4*)WloS)[tid + j * 256] = ((const float4*)Wlo)[tid + j * 256];

    const int wave = tid >> 6, lane = tid & 63;
    const int quad = lane >> 4, l16 = lane & 15;
    const int m0 = blockIdx.x * 128 + wave * 32;

    // load + split A: 2 row-groups x 4 Ksteps x 8 bf16
    short8 Ahi[2][4], Alo[2][4];
#pragma unroll
    for (int r = 0; r < 2; ++r) {
        int row = m0 + r * 16 + l16;
        row = row < M ? row : (M - 1);
        const float* xr = X + (size_t)row * 128 + quad * 8;
#pragma unroll
        for (int s = 0; s < 4; ++s) {
            float4 a = ((const float4*)(xr + s * 32))[0];
            float4 b = ((const float4*)(xr + s * 32))[1];
            float v[8] = {a.x, a.y, a.z, a.w, b.x, b.y, b.z, b.w};
#pragma unroll
            for (int j = 0; j < 8; ++j) {
                unsigned short h = f2bf_rne(v[j]);
                Ahi[r][s][j] = (short)h;
                float res = v[j] - __uint_as_float(((unsigned)h) << 16);
                Alo[r][s][j] = (short)f2bf_rne(res);
            }
        }
    }

    __syncthreads();

    floatx4 acc[2][8];
#pragma unroll
    for (int r = 0; r < 2; ++r)
#pragma unroll
        for (int t = 0; t < 8; ++t) acc[r][t] = (floatx4){0.f, 0.f, 0.f, 0.f};

    const short8* WH = (const short8*)WhiS;
    const short8* WL = (const short8*)WloS;
#pragma unroll
    for (int s = 0; s < 4; ++s) {
#pragma unroll
        for (int t = 0; t < 8; ++t) {
            short8 bh = WH[(t * 4 + s) * 64 + lane];
            short8 bl = WL[(t * 4 + s) * 64 + lane];
#pragma unroll
            for (int r = 0; r < 2; ++r) {
                acc[r][t] = __builtin_amdgcn_mfma_f32_16x16x32_bf16(Ahi[r][s], bh, acc[r][t], 0, 0, 0);
                acc[r][t] = __builtin_amdgcn_mfma_f32_16x16x32_bf16(Alo[r][s], bh, acc[r][t], 0, 0, 0);
                acc[r][t] = __builtin_amdgcn_mfma_f32_16x16x32_bf16(Ahi[r][s], bl, acc[r][t], 0, 0, 0);
            }
        }
    }

    // epilogue: C/D layout col = l16, row = quad*4 + e
    float bcol[8];
    if (BIAS) {
#pragma unroll
        for (int t = 0; t < 8; ++t) bcol[t] = bias[t * 16 + l16];
    }
#pragma unroll
    for (int r = 0; r < 2; ++r) {
#pragma unroll
        for (int e = 0; e < 4; ++e) {
            int row = m0 + r * 16 + quad * 4 + e;
            if (row < M) {
                float sc = SCALE ? scale[row] : 1.f;
                float* yr = Y + (size_t)row * 128 + l16;
#pragma unroll
                for (int t = 0; t < 8; ++t) {
                    float v = acc[r][t][e];
                    if (SCALE) v *= sc;
                    if (BIAS) v += bcol[t];
                    if (RELU) v = fmaxf(v, 0.f);
                    yr[t * 16] = v;
                }
            }
        }
    }
}

// ----------------------------- Aggregate ------------------------------------
// out[i] = op( dinv[i] * (hs[i] + sum_nb hs[col]) + b ), wave/node, float2/lane,
// unroll-8 neighbor gathers for latency hiding.
template <bool RELU>
__global__ __launch_bounds__(256) void agg_k(const float* __restrict__ hs,
                                             const int* __restrict__ row_ptr,
                                             const int* __restrict__ col_idx,
                                             const float* __restrict__ dinv,
                                             const float* __restrict__ bias,
                                             float* __restrict__ out, int n) {
    int wave = blockIdx.x * 4 + (threadIdx.x >> 6);
    int lane = threadIdx.x & 63;
    int nwaves = gridDim.x * 4;
    float2 b2 = ((const float2*)bias)[lane];

    for (int i = wave; i < n; i += nwaves) {
        float2 acc = ((const float2*)(hs + (size_t)i * DFEAT))[lane];  // self loop
        int s = row_ptr[i], e = row_ptr[i + 1];
        for (int base = s; base < e; base += 64) {
            int cnt = min(64, e - base);
            int idx = (base + lane < e) ? col_idx[base + lane] : 0;
            int j = 0;
            for (; j + 8 <= cnt; j += 8) {
                int s0 = __shfl(idx, j + 0), s1 = __shfl(idx, j + 1);
                int s2 = __shfl(idx, j + 2), s3 = __shfl(idx, j + 3);
                int s4 = __shfl(idx, j + 4), s5 = __shfl(idx, j + 5);
                int s6 = __shfl(idx, j + 6), s7 = __shfl(idx, j + 7);
                float2 v0 = ((const float2*)(hs + (size_t)s0 * DFEAT))[lane];
                float2 v1 = ((const float2*)(hs + (size_t)s1 * DFEAT))[lane];
                float2 v2 = ((const float2*)(hs + (size_t)s2 * DFEAT))[lane];
                float2 v3 = ((const float2*)(hs + (size_t)s3 * DFEAT))[lane];
                float2 v4 = ((const float2*)(hs + (size_t)s4 * DFEAT))[lane];
                float2 v5 = ((const float2*)(hs + (size_t)s5 * DFEAT))[lane];
                float2 v6 = ((const float2*)(hs + (size_t)s6 * DFEAT))[lane];
                float2 v7 = ((const float2*)(hs + (size_t)s7 * DFEAT))[lane];
                acc.x += ((v0.x + v1.x) + (v2.x + v3.x)) + ((v4.x + v5.x) + (v6.x + v7.x));
                acc.y += ((v0.y + v1.y) + (v2.y + v3.y)) + ((v4.y + v5.y) + (v6.y + v7.y));
            }
            for (; j + 2 <= cnt; j += 2) {
                int s0 = __shfl(idx, j), s1 = __shfl(idx, j + 1);
                float2 v0 = ((const float2*)(hs + (size_t)s0 * DFEAT))[lane];
                float2 v1 = ((const float2*)(hs + (size_t)s1 * DFEAT))[lane];
                acc.x += v0.x + v1.x;
                acc.y += v0.y + v1.y;
            }
            if (j < cnt) {
                int s0 = __shfl(idx, j);
                float2 v0 = ((const float2*)(hs + (size_t)s0 * DFEAT))[lane];
                acc.x += v0.x;
                acc.y += v0.y;
            }
        }
        float di = dinv[i];
        float ox = fmaf(acc.x, di, b2.x);
        float oy = fmaf(acc.y, di, b2.y);
        if (RELU) { ox = fmaxf(ox, 0.f); oy = fmaxf(oy, 0.f); }
        ((float2*)(out + (size_t)i * DFEAT))[lane] = make_float2(ox, oy);
    }
}

// ---------------------------------------------------------------------------

static inline size_t align_up(size_t x, size_t a) { return (x + a - 1) & ~(a - 1); }

extern "C" void kernel_launch(void* const* d_in, const int* in_sizes, int n_in,
                              void* d_out, int out_size, void* d_ws, size_t ws_size,
                              hipStream_t stream) {
    const float* x  = (const float*)d_in[0];
    const int*   ei = (const int*)d_in[1];
    const float* W0 = (const float*)d_in[2];
    const float* b0 = (const float*)d_in[3];
    const float* W1 = (const float*)d_in[4];
    const float* b1 = (const float*)d_in[5];
    const float* Wv = (const float*)d_in[6];
    const float* bv = (const float*)d_in[7];
    const float* Wt = (const float*)d_in[8];
    const float* bt = (const float*)d_in[9];

    const int N = in_sizes[0] / DFEAT;
    const int E = in_sizes[1] / 2;
    const int* src = ei;
    const int* dst = ei + E;

    const int nchunks = (N + 63) >> 6;

    // workspace carve-up
    char* w = (char*)d_ws;
    int* deg        = (int*)w;  w += align_up((size_t)N * 4, 256);
    int* row_ptr    = (int*)w;  w += align_up((size_t)(N + 1) * 4, 256);
    int* cursor     = (int*)w;  w += align_up((size_t)N * 4, 256);
    int* chunk_sums = (int*)w;  w += align_up((size_t)(nchunks + 1) * 4, 256);
    int* col_idx    = (int*)w;  w += align_up((size_t)E * 4, 256);
    float* dinv     = (float*)w; w += align_up((size_t)N * 4, 256);
    short* w0hi = (short*)w; w += align_up(16384 * 2, 256);
    short* w0lo = (short*)w; w += align_up(16384 * 2, 256);
    short* w1hi = (short*)w; w += align_up(16384 * 2, 256);
    short* w1lo = (short*)w; w += align_up(16384 * 2, 256);
    short* wvhi = (short*)w; w += align_up(16384 * 2, 256);
    short* wvlo = (short*)w; w += align_up(16384 * 2, 256);
    short* wthi = (short*)w; w += align_up(16384 * 2, 256);
    short* wtlo = (short*)w; w += align_up(16384 * 2, 256);
    float* hs       = (float*)w; w += align_up((size_t)N * DFEAT * 4, 256);
    float* h1       = (float*)w; w += align_up((size_t)N * DFEAT * 4, 256);

    float* out_h = (float*)d_out;
    float* out_v = out_h + (size_t)N * DFEAT;
    float* out_t = out_h + 2 * (size_t)N * DFEAT;

    const int eb = (E + 255) / 256;
    const int nb = (N + 255) / 256;
    const int gb = (N + 127) / 128;   // gemm blocks (128 rows/block)
    const int agg_blocks = 2048;      // 8192 waves -> full occupancy

    // CSR build + weight pre-split
    hipMemsetAsync(deg, 0, (size_t)N * 4, stream);
    count_deg_k<<<eb, 256, 0, stream>>>(dst, deg, E);
    prep_w_k<<<64, 256, 0, stream>>>(W0, w0hi, w0lo);
    prep_w_k<<<64, 256, 0, stream>>>(W1, w1hi, w1lo);
    prep_w_k<<<64, 256, 0, stream>>>(Wv, wvhi, wvlo);
    prep_w_k<<<64, 256, 0, stream>>>(Wt, wthi, wtlo);
    scan_local_k<<<(nchunks + 3) / 4, 256, 0, stream>>>(deg, row_ptr, chunk_sums, N);
    scan_chunks_k<<<1, 1024, 0, stream>>>(chunk_sums, nchunks);
    finalize_csr_k<<<nb, 256, 0, stream>>>(row_ptr, chunk_sums, cursor, deg, dinv, N, E);
    fill_csr_k<<<eb, 256, 0, stream>>>(src, dst, cursor, col_idx, E);

    // layer 0
    gemm_mfma_k<true, false, false><<<gb, 256, 0, stream>>>(x, w0hi, w0lo, dinv, nullptr, hs, N);
    agg_k<true><<<agg_blocks, 256, 0, stream>>>(hs, row_ptr, col_idx, dinv, b0, h1, N);
    // layer 1
    gemm_mfma_k<true, false, false><<<gb, 256, 0, stream>>>(h1, w1hi, w1lo, dinv, nullptr, hs, N);
    agg_k<false><<<agg_blocks, 256, 0, stream>>>(hs, row_ptr, col_idx, dinv, b1, out_h, N);
    // heads
    gemm_mfma_k<false, true, true><<<gb, 256, 0, stream>>>(out_h, wvhi, wvlo, nullptr, bv, out_v, N);
    gemm_mfma_k<false, true, true><<<gb, 256, 0, stream>>>(out_h, wthi, wtlo, nullptr, bt, out_t, N);
}

// Round 3
// 360.890 us; speedup vs baseline: 1.2777x; 1.0054x over previous
//
#include <hip/hip_runtime.h>
#include <math.h>

// ---------------------------------------------------------------------------
// GCN 2-layer + two heads, fp32, MI355X.
//   CSR build (histogram + shfl scan) ->
//   GEMMs via split-bf16 MFMA (hi/lo, 3 mfma ~= fp32 precision) ->
//   CSR gather aggregate (float4/lane, 2 nodes/wave, unroll-8).
// ---------------------------------------------------------------------------

#define DFEAT 128

using short8  = __attribute__((ext_vector_type(8))) short;
using floatx4 = __attribute__((ext_vector_type(4))) float;

__device__ __forceinline__ unsigned short f2bf_rne(float x) {
    unsigned u = __float_as_uint(x);
    unsigned r = u + 0x7FFFu + ((u >> 16) & 1u);
    return (unsigned short)(r >> 16);
}

// ---------------------------- CSR build ------------------------------------

__global__ __launch_bounds__(256) void count_deg_k(const int* __restrict__ dst,
                                                   int* __restrict__ deg, int E) {
    int e = blockIdx.x * 256 + threadIdx.x;
    if (e < E) atomicAdd(&deg[dst[e]], 1);
}

__global__ __launch_bounds__(256) void scan_local_k(const int* __restrict__ deg,
                                                    int* __restrict__ row_ptr,
                                                    int* __restrict__ chunk_sums,
                                                    int n) {
    int wave = blockIdx.x * 4 + (threadIdx.x >> 6);
    int lane = threadIdx.x & 63;
    int nchunks = (n + 63) >> 6;
    if (wave >= nchunks) return;
    int i = wave * 64 + lane;
    int v = (i < n) ? deg[i] : 0;
    int x = v;
#pragma unroll
    for (int off = 1; off < 64; off <<= 1) {
        int y = __shfl_up(x, off);
        if (lane >= off) x += y;
    }
    if (i < n) row_ptr[i] = x - v;
    if (lane == 63) chunk_sums[wave] = x;
}

__global__ __launch_bounds__(1024) void scan_chunks_k(int* __restrict__ a, int nchunks) {
    __shared__ int s[1024];
    int tid = threadIdx.x;
    int v = (tid < nchunks) ? a[tid] : 0;
    s[tid] = v;
    __syncthreads();
    int x = v;
    for (int off = 1; off < 1024; off <<= 1) {
        int y = (tid >= off) ? s[tid - off] : 0;
        __syncthreads();
        x += y;
        s[tid] = x;
        __syncthreads();
    }
    if (tid < nchunks) a[tid] = x - v;
}

__global__ __launch_bounds__(256) void finalize_csr_k(int* __restrict__ row_ptr,
                                                      const int* __restrict__ chunk_offs,
                                                      int* __restrict__ cursor,
                                                      const int* __restrict__ deg,
                                                      float* __restrict__ dinv,
                                                      int n, int E) {
    int i = blockIdx.x * 256 + threadIdx.x;
    if (i < n) {
        int rp = row_ptr[i] + chunk_offs[i >> 6];
        row_ptr[i] = rp;
        cursor[i] = rp;
        dinv[i] = rsqrtf((float)(deg[i] + 1));   // +1 self loop
    }
    if (i == 0) row_ptr[n] = E;
}

__global__ __launch_bounds__(256) void fill_csr_k(const int* __restrict__ src,
                                                  const int* __restrict__ dst,
                                                  int* __restrict__ cursor,
                                                  int* __restrict__ col_idx, int E) {
    int e = blockIdx.x * 256 + threadIdx.x;
    if (e < E) {
        int pos = atomicAdd(&cursor[dst[e]], 1);
        col_idx[pos] = src[e];
    }
}

// ------------------------- W pre-split to MFMA frags ------------------------
// Fragment layout (16x16x32 bf16): flat index i = ((t*4+s)*64 + lane)*8 + j,
// element B[k][n], n = t*16 + (lane&15), k = s*32 + (lane>>4)*8 + j.
// One kernel handles all 4 weight matrices (grid = 4 * 64 blocks).
__global__ __launch_bounds__(256) void prep_w4_k(const float* __restrict__ W0,
                                                 const float* __restrict__ W1,
                                                 const float* __restrict__ W2,
                                                 const float* __restrict__ W3,
                                                 short* __restrict__ hi_all,
                                                 short* __restrict__ lo_all) {
    int b = blockIdx.x >> 6;                     // weight id 0..3
    const float* W = (b == 0) ? W0 : (b == 1) ? W1 : (b == 2) ? W2 : W3;
    short* hi = hi_all + (size_t)b * 16384;
    short* lo = lo_all + (size_t)b * 16384;
    int i = (blockIdx.x & 63) * 256 + threadIdx.x;  // 0..16383
    int j = i & 7;
    int lane = (i >> 3) & 63;
    int ts = i >> 9;
    int s = ts & 3, t = ts >> 2;
    int k = s * 32 + (lane >> 4) * 8 + j;
    int n = t * 16 + (lane & 15);
    float x = W[k * 128 + n];
    unsigned short h = f2bf_rne(x);
    float res = x - __uint_as_float(((unsigned)h) << 16);
    hi[i] = (short)h;
    lo[i] = (short)f2bf_rne(res);
}

// ----------------------- GEMM via split-bf16 MFMA ---------------------------
template <bool SCALE, bool BIAS, bool RELU>
__global__ __launch_bounds__(256) void gemm_mfma_k(const float* __restrict__ X,
                                                   const short* __restrict__ Whi,
                                                   const short* __restrict__ Wlo,
                                                   const float* __restrict__ scale,
                                                   const float* __restrict__ bias,
                                                   float* __restrict__ Y, int M) {
    __shared__ short WhiS[16384];
    __shared__ short WloS[16384];
    const int tid = threadIdx.x;

#pragma unroll
    for (int j = 0; j < 8; ++j)
        ((float4*)WhiS)[tid + j * 256] = ((const float4*)Whi)[tid + j * 256];
#pragma unroll
    for (int j = 0; j < 8; ++j)
        ((float4*)WloS)[tid + j * 256] = ((const float4*)Wlo)[tid + j * 256];

    const int wave = tid >> 6, lane = tid & 63;
    const int quad = lane >> 4, l16 = lane & 15;
    const int m0 = blockIdx.x * 128 + wave * 32;

    short8 Ahi[2][4], Alo[2][4];
#pragma unroll
    for (int r = 0; r < 2; ++r) {
        int row = m0 + r * 16 + l16;
        row = row < M ? row : (M - 1);
        const float* xr = X + (size_t)row * 128 + quad * 8;
#pragma unroll
        for (int s = 0; s < 4; ++s) {
            float4 a = ((const float4*)(xr + s * 32))[0];
            float4 b = ((const float4*)(xr + s * 32))[1];
            float v[8] = {a.x, a.y, a.z, a.w, b.x, b.y, b.z, b.w};
#pragma unroll
            for (int j = 0; j < 8; ++j) {
                unsigned short h = f2bf_rne(v[j]);
                Ahi[r][s][j] = (short)h;
                float res = v[j] - __uint_as_float(((unsigned)h) << 16);
                Alo[r][s][j] = (short)f2bf_rne(res);
            }
        }
    }

    __syncthreads();

    floatx4 acc[2][8];
#pragma unroll
    for (int r = 0; r < 2; ++r)
#pragma unroll
        for (int t = 0; t < 8; ++t) acc[r][t] = (floatx4){0.f, 0.f, 0.f, 0.f};

    const short8* WH = (const short8*)WhiS;
    const short8* WL = (const short8*)WloS;
#pragma unroll
    for (int s = 0; s < 4; ++s) {
#pragma unroll
        for (int t = 0; t < 8; ++t) {
            short8 bh = WH[(t * 4 + s) * 64 + lane];
            short8 bl = WL[(t * 4 + s) * 64 + lane];
#pragma unroll
            for (int r = 0; r < 2; ++r) {
                acc[r][t] = __builtin_amdgcn_mfma_f32_16x16x32_bf16(Ahi[r][s], bh, acc[r][t], 0, 0, 0);
                acc[r][t] = __builtin_amdgcn_mfma_f32_16x16x32_bf16(Alo[r][s], bh, acc[r][t], 0, 0, 0);
                acc[r][t] = __builtin_amdgcn_mfma_f32_16x16x32_bf16(Ahi[r][s], bl, acc[r][t], 0, 0, 0);
            }
        }
    }

    float bcol[8];
    if (BIAS) {
#pragma unroll
        for (int t = 0; t < 8; ++t) bcol[t] = bias[t * 16 + l16];
    }
#pragma unroll
    for (int r = 0; r < 2; ++r) {
#pragma unroll
        for (int e = 0; e < 4; ++e) {
            int row = m0 + r * 16 + quad * 4 + e;
            if (row < M) {
                float sc = SCALE ? scale[row] : 1.f;
                float* yr = Y + (size_t)row * 128 + l16;
#pragma unroll
                for (int t = 0; t < 8; ++t) {
                    float v = acc[r][t][e];
                    if (SCALE) v *= sc;
                    if (BIAS) v += bcol[t];
                    if (RELU) v = fmaxf(v, 0.f);
                    yr[t * 16] = v;
                }
            }
        }
    }
}

// ----------------------------- Aggregate ------------------------------------
// out[i] = op( dinv[i]*(hs[i] + sum_nb hs[col]) + b ).  float4 per lane,
// TWO nodes per wave (half-wave each, 32 lanes x 16B = one 512B row per half).
// Unroll-8 -> 16 neighbor rows (8KB) in flight per wave.
template <bool RELU>
__global__ __launch_bounds__(256) void agg_k(const float* __restrict__ hs,
                                             const int* __restrict__ row_ptr,
                                             const int* __restrict__ col_idx,
                                             const float* __restrict__ dinv,
                                             const float* __restrict__ bias,
                                             float* __restrict__ out, int n) {
    int wv = blockIdx.x * 4 + (threadIdx.x >> 6);
    int lane = threadIdx.x & 63;
    int half = lane >> 5, l32 = lane & 31;
    int nw = gridDim.x * 4;
    int npair = (n + 1) >> 1;
    float4 b4 = ((const float4*)bias)[l32];

    for (int p = wv; p < npair; p += nw) {
        int node = p * 2 + half;
        bool vnode = node < n;
        int nc = vnode ? node : (n - 1);
        float4 acc = ((const float4*)(hs + (size_t)nc * DFEAT))[l32];   // self loop
        int s = row_ptr[nc];
        int cnt = vnode ? (row_ptr[nc + 1] - s) : 0;
        int mc = max(cnt, __shfl(cnt, lane ^ 32));   // max over the two halves

        for (int base = 0; base < mc; base += 32) {
            int t = base + l32;
            int idx = (t < cnt) ? col_idx[s + t] : -1;
            int lim = mc - base; lim = lim > 32 ? 32 : lim;
#pragma unroll
            for (int j = 0; j < 32; j += 8) {
                if (j >= lim) break;
                int ia[8];
#pragma unroll
                for (int k = 0; k < 8; ++k)
                    ia[k] = __shfl(idx, half * 32 + j + k);
#pragma unroll
                for (int k = 0; k < 8; ++k) {
                    int ii = ia[k];
                    float msk = (ii >= 0) ? 1.f : 0.f;
                    int addr = (ii >= 0) ? ii : nc;
                    float4 v = ((const float4*)(hs + (size_t)addr * DFEAT))[l32];
                    acc.x = fmaf(v.x, msk, acc.x);
                    acc.y = fmaf(v.y, msk, acc.y);
                    acc.z = fmaf(v.z, msk, acc.z);
                    acc.w = fmaf(v.w, msk, acc.w);
                }
            }
        }
        float di = dinv[nc];
        float4 o;
        o.x = fmaf(acc.x, di, b4.x);
        o.y = fmaf(acc.y, di, b4.y);
        o.z = fmaf(acc.z, di, b4.z);
        o.w = fmaf(acc.w, di, b4.w);
        if (RELU) {
            o.x = fmaxf(o.x, 0.f); o.y = fmaxf(o.y, 0.f);
            o.z = fmaxf(o.z, 0.f); o.w = fmaxf(o.w, 0.f);
        }
        if (vnode) ((float4*)(out + (size_t)nc * DFEAT))[l32] = o;
    }
}

// ---------------------------------------------------------------------------

static inline size_t align_up(size_t x, size_t a) { return (x + a - 1) & ~(a - 1); }

extern "C" void kernel_launch(void* const* d_in, const int* in_sizes, int n_in,
                              void* d_out, int out_size, void* d_ws, size_t ws_size,
                              hipStream_t stream) {
    const float* x  = (const float*)d_in[0];
    const int*   ei = (const int*)d_in[1];
    const float* W0 = (const float*)d_in[2];
    const float* b0 = (const float*)d_in[3];
    const float* W1 = (const float*)d_in[4];
    const float* b1 = (const float*)d_in[5];
    const float* Wv = (const float*)d_in[6];
    const float* bv = (const float*)d_in[7];
    const float* Wt = (const float*)d_in[8];
    const float* bt = (const float*)d_in[9];

    const int N = in_sizes[0] / DFEAT;
    const int E = in_sizes[1] / 2;
    const int* src = ei;
    const int* dst = ei + E;

    const int nchunks = (N + 63) >> 6;

    // workspace carve-up
    char* w = (char*)d_ws;
    int* deg        = (int*)w;  w += align_up((size_t)N * 4, 256);
    int* row_ptr    = (int*)w;  w += align_up((size_t)(N + 1) * 4, 256);
    int* cursor     = (int*)w;  w += align_up((size_t)N * 4, 256);
    int* chunk_sums = (int*)w;  w += align_up((size_t)(nchunks + 1) * 4, 256);
    int* col_idx    = (int*)w;  w += align_up((size_t)E * 4, 256);
    float* dinv     = (float*)w; w += align_up((size_t)N * 4, 256);
    short* whi_all  = (short*)w; w += align_up(4 * 16384 * 2, 256);
    short* wlo_all  = (short*)w; w += align_up(4 * 16384 * 2, 256);
    float* hs       = (float*)w; w += align_up((size_t)N * DFEAT * 4, 256);
    float* h1       = (float*)w; w += align_up((size_t)N * DFEAT * 4, 256);

    short* w0hi = whi_all;            short* w0lo = wlo_all;
    short* w1hi = whi_all + 16384;    short* w1lo = wlo_all + 16384;
    short* wvhi = whi_all + 2*16384;  short* wvlo = wlo_all + 2*16384;
    short* wthi = whi_all + 3*16384;  short* wtlo = wlo_all + 3*16384;

    float* out_h = (float*)d_out;
    float* out_v = out_h + (size_t)N * DFEAT;
    float* out_t = out_h + 2 * (size_t)N * DFEAT;

    const int eb = (E + 255) / 256;
    const int nb = (N + 255) / 256;
    const int gb = (N + 127) / 128;
    const int agg_blocks = 2048;

    // CSR build + weight pre-split
    hipMemsetAsync(deg, 0, (size_t)N * 4, stream);
    count_deg_k<<<eb, 256, 0, stream>>>(dst, deg, E);
    prep_w4_k<<<256, 256, 0, stream>>>(W0, W1, Wv, Wt, whi_all, wlo_all);
    scan_local_k<<<(nchunks + 3) / 4, 256, 0, stream>>>(deg, row_ptr, chunk_sums, N);
    scan_chunks_k<<<1, 1024, 0, stream>>>(chunk_sums, nchunks);
    finalize_csr_k<<<nb, 256, 0, stream>>>(row_ptr, chunk_sums, cursor, deg, dinv, N, E);
    fill_csr_k<<<eb, 256, 0, stream>>>(src, dst, cursor, col_idx, E);

    // layer 0
    gemm_mfma_k<true, false, false><<<gb, 256, 0, stream>>>(x, w0hi, w0lo, dinv, nullptr, hs, N);
    agg_k<true><<<agg_blocks, 256, 0, stream>>>(hs, row_ptr, col_idx, dinv, b0, h1, N);
    // layer 1
    gemm_mfma_k<true, false, false><<<gb, 256, 0, stream>>>(h1, w1hi, w1lo, dinv, nullptr, hs, N);
    agg_k<false><<<agg_blocks, 256, 0, stream>>>(hs, row_ptr, col_idx, dinv, b1, out_h, N);
    // heads
    gemm_mfma_k<false, true, true><<<gb, 256, 0, stream>>>(out_h, wvhi, wvlo, nullptr, bv, out_v, N);
    gemm_mfma_k<false, true, true><<<gb, 256, 0, stream>>>(out_h, wthi, wtlo, nullptr, bt, out_t, N);
}

// Round 4
// 299.069 us; speedup vs baseline: 1.5418x; 1.2067x over previous
//
#include <hip/hip_runtime.h>
#include <hip/hip_fp16.h>
#include <math.h>

// ---------------------------------------------------------------------------
// GCN 2-layer + two heads, fp32 in/out, MI355X.
//   CSR build -> GEMMs via split-bf16 MFMA (3 mfma ~= fp32) ->
//   CSR gather aggregate over fp16-compressed node features
//   (halves the per-XCD L2 fill traffic, which round-3 counters showed to be
//    the structural cost: FETCH ~= 8 XCD x sizeof(hs)).
// ---------------------------------------------------------------------------

#define DFEAT 128

using short8  = __attribute__((ext_vector_type(8))) short;
using floatx4 = __attribute__((ext_vector_type(4))) float;

__device__ __forceinline__ unsigned short f2bf_rne(float x) {
    unsigned u = __float_as_uint(x);
    unsigned r = u + 0x7FFFu + ((u >> 16) & 1u);
    return (unsigned short)(r >> 16);
}

// ---------------------------- CSR build ------------------------------------

__global__ __launch_bounds__(256) void count_deg_k(const int* __restrict__ dst,
                                                   int* __restrict__ deg, int E) {
    int e = blockIdx.x * 256 + threadIdx.x;
    if (e < E) atomicAdd(&deg[dst[e]], 1);
}

__global__ __launch_bounds__(256) void scan_local_k(const int* __restrict__ deg,
                                                    int* __restrict__ row_ptr,
                                                    int* __restrict__ chunk_sums,
                                                    int n) {
    int wave = blockIdx.x * 4 + (threadIdx.x >> 6);
    int lane = threadIdx.x & 63;
    int nchunks = (n + 63) >> 6;
    if (wave >= nchunks) return;
    int i = wave * 64 + lane;
    int v = (i < n) ? deg[i] : 0;
    int x = v;
#pragma unroll
    for (int off = 1; off < 64; off <<= 1) {
        int y = __shfl_up(x, off);
        if (lane >= off) x += y;
    }
    if (i < n) row_ptr[i] = x - v;
    if (lane == 63) chunk_sums[wave] = x;
}

__global__ __launch_bounds__(1024) void scan_chunks_k(int* __restrict__ a, int nchunks) {
    __shared__ int s[1024];
    int tid = threadIdx.x;
    int v = (tid < nchunks) ? a[tid] : 0;
    s[tid] = v;
    __syncthreads();
    int x = v;
    for (int off = 1; off < 1024; off <<= 1) {
        int y = (tid >= off) ? s[tid - off] : 0;
        __syncthreads();
        x += y;
        s[tid] = x;
        __syncthreads();
    }
    if (tid < nchunks) a[tid] = x - v;
}

__global__ __launch_bounds__(256) void finalize_csr_k(int* __restrict__ row_ptr,
                                                      const int* __restrict__ chunk_offs,
                                                      int* __restrict__ cursor,
                                                      const int* __restrict__ deg,
                                                      float* __restrict__ dinv,
                                                      int n, int E) {
    int i = blockIdx.x * 256 + threadIdx.x;
    if (i < n) {
        int rp = row_ptr[i] + chunk_offs[i >> 6];
        row_ptr[i] = rp;
        cursor[i] = rp;
        dinv[i] = rsqrtf((float)(deg[i] + 1));   // +1 self loop
    }
    if (i == 0) row_ptr[n] = E;
}

__global__ __launch_bounds__(256) void fill_csr_k(const int* __restrict__ src,
                                                  const int* __restrict__ dst,
                                                  int* __restrict__ cursor,
                                                  int* __restrict__ col_idx, int E) {
    int e = blockIdx.x * 256 + threadIdx.x;
    if (e < E) {
        int pos = atomicAdd(&cursor[dst[e]], 1);
        col_idx[pos] = src[e];
    }
}

// ------------------------- W pre-split to MFMA frags ------------------------
// flat index i = ((t*4+s)*64 + lane)*8 + j -> B[k][n], n = t*16 + (lane&15),
// k = s*32 + (lane>>4)*8 + j.
__global__ __launch_bounds__(256) void prep_w4_k(const float* __restrict__ W0,
                                                 const float* __restrict__ W1,
                                                 const float* __restrict__ W2,
                                                 const float* __restrict__ W3,
                                                 short* __restrict__ hi_all,
                                                 short* __restrict__ lo_all) {
    int b = blockIdx.x >> 6;
    const float* W = (b == 0) ? W0 : (b == 1) ? W1 : (b == 2) ? W2 : W3;
    short* hi = hi_all + (size_t)b * 16384;
    short* lo = lo_all + (size_t)b * 16384;
    int i = (blockIdx.x & 63) * 256 + threadIdx.x;
    int j = i & 7;
    int lane = (i >> 3) & 63;
    int ts = i >> 9;
    int s = ts & 3, t = ts >> 2;
    int k = s * 32 + (lane >> 4) * 8 + j;
    int n = t * 16 + (lane & 15);
    float x = W[k * 128 + n];
    unsigned short h = f2bf_rne(x);
    float res = x - __uint_as_float(((unsigned)h) << 16);
    hi[i] = (short)h;
    lo[i] = (short)f2bf_rne(res);
}

// ----------------------- GEMM via split-bf16 MFMA ---------------------------
template <typename InT, typename OutT, bool SCALE, bool BIAS, bool RELU>
__device__ __forceinline__ void gemm_core(const InT* __restrict__ X,
                                          const short* __restrict__ Whi,
                                          const short* __restrict__ Wlo,
                                          const float* __restrict__ scale,
                                          const float* __restrict__ bias,
                                          OutT* __restrict__ Y, int M, int blk) {
    __shared__ short WhiS[16384];
    __shared__ short WloS[16384];
    const int tid = threadIdx.x;

#pragma unroll
    for (int j = 0; j < 8; ++j)
        ((float4*)WhiS)[tid + j * 256] = ((const float4*)Whi)[tid + j * 256];
#pragma unroll
    for (int j = 0; j < 8; ++j)
        ((float4*)WloS)[tid + j * 256] = ((const float4*)Wlo)[tid + j * 256];

    const int wave = tid >> 6, lane = tid & 63;
    const int quad = lane >> 4, l16 = lane & 15;
    const int m0 = blk * 128 + wave * 32;

    short8 Ahi[2][4], Alo[2][4];
#pragma unroll
    for (int r = 0; r < 2; ++r) {
        int row = m0 + r * 16 + l16;
        row = row < M ? row : (M - 1);
        const InT* xr = X + (size_t)row * 128 + quad * 8;
#pragma unroll
        for (int s = 0; s < 4; ++s) {
            float v[8];
            if constexpr (sizeof(InT) == 4) {
                float4 a = ((const float4*)(xr + s * 32))[0];
                float4 b = ((const float4*)(xr + s * 32))[1];
                v[0] = a.x; v[1] = a.y; v[2] = a.z; v[3] = a.w;
                v[4] = b.x; v[5] = b.y; v[6] = b.z; v[7] = b.w;
            } else {
                uint4 raw = *(const uint4*)(xr + s * 32);
                const __half2* hp = (const __half2*)&raw;
#pragma unroll
                for (int k = 0; k < 4; ++k) {
                    float2 f = __half22float2(hp[k]);
                    v[2 * k] = f.x; v[2 * k + 1] = f.y;
                }
            }
#pragma unroll
            for (int j = 0; j < 8; ++j) {
                unsigned short h = f2bf_rne(v[j]);
                Ahi[r][s][j] = (short)h;
                float res = v[j] - __uint_as_float(((unsigned)h) << 16);
                Alo[r][s][j] = (short)f2bf_rne(res);
            }
        }
    }

    __syncthreads();

    floatx4 acc[2][8];
#pragma unroll
    for (int r = 0; r < 2; ++r)
#pragma unroll
        for (int t = 0; t < 8; ++t) acc[r][t] = (floatx4){0.f, 0.f, 0.f, 0.f};

    const short8* WH = (const short8*)WhiS;
    const short8* WL = (const short8*)WloS;
#pragma unroll
    for (int s = 0; s < 4; ++s) {
#pragma unroll
        for (int t = 0; t < 8; ++t) {
            short8 bh = WH[(t * 4 + s) * 64 + lane];
            short8 bl = WL[(t * 4 + s) * 64 + lane];
#pragma unroll
            for (int r = 0; r < 2; ++r) {
                acc[r][t] = __builtin_amdgcn_mfma_f32_16x16x32_bf16(Ahi[r][s], bh, acc[r][t], 0, 0, 0);
                acc[r][t] = __builtin_amdgcn_mfma_f32_16x16x32_bf16(Alo[r][s], bh, acc[r][t], 0, 0, 0);
                acc[r][t] = __builtin_amdgcn_mfma_f32_16x16x32_bf16(Ahi[r][s], bl, acc[r][t], 0, 0, 0);
            }
        }
    }

    float bcol[8];
    if (BIAS) {
#pragma unroll
        for (int t = 0; t < 8; ++t) bcol[t] = bias[t * 16 + l16];
    }
#pragma unroll
    for (int r = 0; r < 2; ++r) {
#pragma unroll
        for (int e = 0; e < 4; ++e) {
            int row = m0 + r * 16 + quad * 4 + e;
            if (row < M) {
                float sc = SCALE ? scale[row] : 1.f;
                OutT* yr = Y + (size_t)row * 128 + l16;
#pragma unroll
                for (int t = 0; t < 8; ++t) {
                    float v = acc[r][t][e];
                    if (SCALE) v *= sc;
                    if (BIAS) v += bcol[t];
                    if (RELU) v = fmaxf(v, 0.f);
                    if constexpr (sizeof(OutT) == 4) yr[t * 16] = v;
                    else yr[t * 16] = __float2half(v);
                }
            }
        }
    }
}

template <typename InT, typename OutT, bool SCALE, bool BIAS, bool RELU>
__global__ __launch_bounds__(256) void gemm_k(const InT* __restrict__ X,
                                              const short* __restrict__ Whi,
                                              const short* __restrict__ Wlo,
                                              const float* __restrict__ scale,
                                              const float* __restrict__ bias,
                                              OutT* __restrict__ Y, int M) {
    gemm_core<InT, OutT, SCALE, BIAS, RELU>(X, Whi, Wlo, scale, bias, Y, M, blockIdx.x);
}

// Two heads in one dispatch: blocks [0,gb) -> vision, [gb,2gb) -> text.
__global__ __launch_bounds__(256) void gemm_heads_k(const float* __restrict__ X,
                                                    const short* __restrict__ WhiV,
                                                    const short* __restrict__ WloV,
                                                    const short* __restrict__ WhiT,
                                                    const short* __restrict__ WloT,
                                                    const float* __restrict__ bv,
                                                    const float* __restrict__ bt,
                                                    float* __restrict__ Yv,
                                                    float* __restrict__ Yt,
                                                    int M, int gb) {
    bool second = blockIdx.x >= gb;
    const short* hi = second ? WhiT : WhiV;
    const short* lo = second ? WloT : WloV;
    const float* b  = second ? bt : bv;
    float* Y        = second ? Yt : Yv;
    int blk         = second ? (blockIdx.x - gb) : blockIdx.x;
    gemm_core<float, float, false, true, true>(X, hi, lo, nullptr, b, Y, M, blk);
}

// ----------------------------- Aggregate ------------------------------------
// out[i] = op( dinv[i]*(hs[i] + sum_nb hs[col]) + b ), hs in fp16.
// One node per wave. lane = 16*g + c: group g loads 16B (8 halves, cols c*8..)
// of a different neighbor -> 4 rows (1KB) per load instr, 4 loads unrolled.
// Cross-group reduce via shfl_xor(16/32); group 0 writes the row.
template <bool RELU, typename OutT>
__global__ __launch_bounds__(256) void agg_k(const __half* __restrict__ hs,
                                             const int* __restrict__ row_ptr,
                                             const int* __restrict__ col_idx,
                                             const float* __restrict__ dinv,
                                             const float* __restrict__ bias,
                                             OutT* __restrict__ out, int n) {
    int wv = blockIdx.x * 4 + (threadIdx.x >> 6);
    int lane = threadIdx.x & 63;
    int g = lane >> 4, c = lane & 15;
    int nw = gridDim.x * 4;

    for (int i = wv; i < n; i += nw) {
        float acc[8];
        // self loop (group 0 only; reduction adds it once)
        if (g == 0) {
            uint4 raw = ((const uint4*)(hs + (size_t)i * DFEAT))[c];
            const __half2* hp = (const __half2*)&raw;
#pragma unroll
            for (int k = 0; k < 4; ++k) {
                float2 f = __half22float2(hp[k]);
                acc[2 * k] = f.x; acc[2 * k + 1] = f.y;
            }
        } else {
#pragma unroll
            for (int k = 0; k < 8; ++k) acc[k] = 0.f;
        }

        int s = row_ptr[i];
        int cnt = row_ptr[i + 1] - s;

        for (int base = 0; base < cnt; base += 64) {
            int t = base + lane;
            int idx = (t < cnt) ? col_idx[s + t] : 0;
            int lim = cnt - base; if (lim > 64) lim = 64;
            for (int j = 0; j < lim; j += 16) {
                int sl0 = j + g, sl1 = j + 4 + g, sl2 = j + 8 + g, sl3 = j + 12 + g;
                int i0 = __shfl(idx, sl0), i1 = __shfl(idx, sl1);
                int i2 = __shfl(idx, sl2), i3 = __shfl(idx, sl3);
                float m0 = sl0 < lim ? 1.f : 0.f;
                float m1 = sl1 < lim ? 1.f : 0.f;
                float m2 = sl2 < lim ? 1.f : 0.f;
                float m3 = sl3 < lim ? 1.f : 0.f;
                uint4 v0 = ((const uint4*)(hs + (size_t)(sl0 < lim ? i0 : i) * DFEAT))[c];
                uint4 v1 = ((const uint4*)(hs + (size_t)(sl1 < lim ? i1 : i) * DFEAT))[c];
                uint4 v2 = ((const uint4*)(hs + (size_t)(sl2 < lim ? i2 : i) * DFEAT))[c];
                uint4 v3 = ((const uint4*)(hs + (size_t)(sl3 < lim ? i3 : i) * DFEAT))[c];
                const __half2* p0 = (const __half2*)&v0;
                const __half2* p1 = (const __half2*)&v1;
                const __half2* p2 = (const __half2*)&v2;
                const __half2* p3 = (const __half2*)&v3;
#pragma unroll
                for (int k = 0; k < 4; ++k) {
                    float2 f0 = __half22float2(p0[k]);
                    float2 f1 = __half22float2(p1[k]);
                    float2 f2 = __half22float2(p2[k]);
                    float2 f3 = __half22float2(p3[k]);
                    acc[2 * k]     = fmaf(f0.x, m0, acc[2 * k]);
                    acc[2 * k + 1] = fmaf(f0.y, m0, acc[2 * k + 1]);
                    acc[2 * k]     = fmaf(f1.x, m1, acc[2 * k]);
                    acc[2 * k + 1] = fmaf(f1.y, m1, acc[2 * k + 1]);
                    acc[2 * k]     = fmaf(f2.x, m2, acc[2 * k]);
                    acc[2 * k + 1] = fmaf(f2.y, m2, acc[2 * k + 1]);
                    acc[2 * k]     = fmaf(f3.x, m3, acc[2 * k]);
                    acc[2 * k + 1] = fmaf(f3.y, m3, acc[2 * k + 1]);
                }
            }
        }

        // reduce the 4 groups
#pragma unroll
        for (int k = 0; k < 8; ++k) {
            acc[k] += __shfl_xor(acc[k], 16);
            acc[k] += __shfl_xor(acc[k], 32);
        }

        if (g == 0) {
            float di = dinv[i];
            float4 b0 = ((const float4*)bias)[c * 2];
            float4 b1 = ((const float4*)bias)[c * 2 + 1];
            float o[8];
            o[0] = fmaf(acc[0], di, b0.x); o[1] = fmaf(acc[1], di, b0.y);
            o[2] = fmaf(acc[2], di, b0.z); o[3] = fmaf(acc[3], di, b0.w);
            o[4] = fmaf(acc[4], di, b1.x); o[5] = fmaf(acc[5], di, b1.y);
            o[6] = fmaf(acc[6], di, b1.z); o[7] = fmaf(acc[7], di, b1.w);
            if (RELU) {
#pragma unroll
                for (int k = 0; k < 8; ++k) o[k] = fmaxf(o[k], 0.f);
            }
            if constexpr (sizeof(OutT) == 4) {
                float4 w0 = make_float4(o[0], o[1], o[2], o[3]);
                float4 w1 = make_float4(o[4], o[5], o[6], o[7]);
                ((float4*)((float*)out + (size_t)i * DFEAT))[c * 2] = w0;
                ((float4*)((float*)out + (size_t)i * DFEAT))[c * 2 + 1] = w1;
            } else {
                __half2 hpk[4];
#pragma unroll
                for (int k = 0; k < 4; ++k)
                    hpk[k] = __floats2half2_rn(o[2 * k], o[2 * k + 1]);
                ((uint4*)((__half*)out + (size_t)i * DFEAT))[c] = *(uint4*)hpk;
            }
        }
    }
}

// ---------------------------------------------------------------------------

static inline size_t align_up(size_t x, size_t a) { return (x + a - 1) & ~(a - 1); }

extern "C" void kernel_launch(void* const* d_in, const int* in_sizes, int n_in,
                              void* d_out, int out_size, void* d_ws, size_t ws_size,
                              hipStream_t stream) {
    const float* x  = (const float*)d_in[0];
    const int*   ei = (const int*)d_in[1];
    const float* W0 = (const float*)d_in[2];
    const float* b0 = (const float*)d_in[3];
    const float* W1 = (const float*)d_in[4];
    const float* b1 = (const float*)d_in[5];
    const float* Wv = (const float*)d_in[6];
    const float* bv = (const float*)d_in[7];
    const float* Wt = (const float*)d_in[8];
    const float* bt = (const float*)d_in[9];

    const int N = in_sizes[0] / DFEAT;
    const int E = in_sizes[1] / 2;
    const int* src = ei;
    const int* dst = ei + E;

    const int nchunks = (N + 63) >> 6;

    // workspace carve-up
    char* w = (char*)d_ws;
    int* deg        = (int*)w;  w += align_up((size_t)N * 4, 256);
    int* row_ptr    = (int*)w;  w += align_up((size_t)(N + 1) * 4, 256);
    int* cursor     = (int*)w;  w += align_up((size_t)N * 4, 256);
    int* chunk_sums = (int*)w;  w += align_up((size_t)(nchunks + 1) * 4, 256);
    int* col_idx    = (int*)w;  w += align_up((size_t)E * 4, 256);
    float* dinv     = (float*)w; w += align_up((size_t)N * 4, 256);
    short* whi_all  = (short*)w; w += align_up(4 * 16384 * 2, 256);
    short* wlo_all  = (short*)w; w += align_up(4 * 16384 * 2, 256);
    __half* hs      = (__half*)w; w += align_up((size_t)N * DFEAT * 2, 256);
    __half* h1      = (__half*)w; w += align_up((size_t)N * DFEAT * 2, 256);

    short* w0hi = whi_all;            short* w0lo = wlo_all;
    short* w1hi = whi_all + 16384;    short* w1lo = wlo_all + 16384;
    short* wvhi = whi_all + 2*16384;  short* wvlo = wlo_all + 2*16384;
    short* wthi = whi_all + 3*16384;  short* wtlo = wlo_all + 3*16384;

    float* out_h = (float*)d_out;
    float* out_v = out_h + (size_t)N * DFEAT;
    float* out_t = out_h + 2 * (size_t)N * DFEAT;

    const int eb = (E + 255) / 256;
    const int nb = (N + 255) / 256;
    const int gb = (N + 127) / 128;
    const int agg_blocks = 2048;

    // CSR build + weight pre-split
    hipMemsetAsync(deg, 0, (size_t)N * 4, stream);
    count_deg_k<<<eb, 256, 0, stream>>>(dst, deg, E);
    prep_w4_k<<<256, 256, 0, stream>>>(W0, W1, Wv, Wt, whi_all, wlo_all);
    scan_local_k<<<(nchunks + 3) / 4, 256, 0, stream>>>(deg, row_ptr, chunk_sums, N);
    scan_chunks_k<<<1, 1024, 0, stream>>>(chunk_sums, nchunks);
    finalize_csr_k<<<nb, 256, 0, stream>>>(row_ptr, chunk_sums, cursor, deg, dinv, N, E);
    fill_csr_k<<<eb, 256, 0, stream>>>(src, dst, cursor, col_idx, E);

    // layer 0: hs = fp16( dinv * (x @ W0) )
    gemm_k<float, __half, true, false, false><<<gb, 256, 0, stream>>>(x, w0hi, w0lo, dinv, nullptr, hs, N);
    // h1 = fp16( relu(dinv * agg(hs) + b0) )
    agg_k<true, __half><<<agg_blocks, 256, 0, stream>>>(hs, row_ptr, col_idx, dinv, b0, h1, N);
    // layer 1: hs = fp16( dinv * (h1 @ W1) )
    gemm_k<__half, __half, true, false, false><<<gb, 256, 0, stream>>>(h1, w1hi, w1lo, dinv, nullptr, hs, N);
    // h = dinv * agg(hs) + b1 -> d_out (fp32)
    agg_k<false, float><<<agg_blocks, 256, 0, stream>>>(hs, row_ptr, col_idx, dinv, b1, out_h, N);
    // heads (fused dispatch)
    gemm_heads_k<<<2 * gb, 256, 0, stream>>>(out_h, wvhi, wvlo, wthi, wtlo, bv, bt, out_v, out_t, N, gb);
}